// Round 13
// baseline (653.646 us; speedup 1.0000x reference)
//
#include <hip/hip_runtime.h>
#include <hip/hip_fp16.h>

#define NNODES 60000
#define NEDGES 960000
#define NGRAPH 10000

struct __align__(16) H8 { __half2 h[4]; };
struct __align__(8)  H4 { __half2 h[2]; };

typedef _Float16 f16x8 __attribute__((ext_vector_type(8)));
typedef float f32x4 __attribute__((ext_vector_type(4)));

#define LDA 264   // halves; 528 B row stride (16B-aligned rows)

// ---------------- degree / CSR build ----------------

__global__ void count_deg_k(const int* __restrict__ ei, int* __restrict__ deg) {
  int e = blockIdx.x * blockDim.x + threadIdx.x;
  atomicAdd(&deg[ei[NEDGES + e]], 1);
}

__global__ void scan1_k(const int* __restrict__ deg, int* __restrict__ rs,
                        int* __restrict__ bsum, float* __restrict__ dinv) {
  __shared__ int s[256];
  int tid = threadIdx.x;
  int i = blockIdx.x * 256 + tid;
  int v = (i < NNODES) ? deg[i] : 0;
  if (i < NNODES) dinv[i] = rsqrtf((float)v + 1.0f);
  int x = v;
  s[tid] = x; __syncthreads();
  #pragma unroll
  for (int off = 1; off < 256; off <<= 1) {
    int t = (tid >= off) ? s[tid - off] : 0;
    __syncthreads();
    x += t; s[tid] = x; __syncthreads();
  }
  if (i < NNODES) rs[i] = x - v;
  if (tid == 255) bsum[blockIdx.x] = x;
}

__global__ void scan2_k(int* __restrict__ bsum, int nb) {
  __shared__ int s[256];
  int tid = threadIdx.x;
  int v = (tid < nb) ? bsum[tid] : 0;
  int x = v; s[tid] = x; __syncthreads();
  #pragma unroll
  for (int off = 1; off < 256; off <<= 1) {
    int t = (tid >= off) ? s[tid - off] : 0;
    __syncthreads();
    x += t; s[tid] = x; __syncthreads();
  }
  if (tid < nb) bsum[tid] = x - v;
}

__global__ void scan3_k(int* __restrict__ rs, const int* __restrict__ bsum) {
  int i = blockIdx.x * 256 + threadIdx.x;
  if (i < NNODES) rs[i] += bsum[blockIdx.x];
  if (i == 0) rs[NNODES] = NEDGES;
}

__global__ void scatter_k(const int* __restrict__ ei, const int* __restrict__ rs,
                          int* __restrict__ cursor, unsigned short* __restrict__ csr) {
  int e = blockIdx.x * blockDim.x + threadIdx.x;
  int s = ei[e], d = ei[NEDGES + e];
  int pos = rs[d] + atomicAdd(&cursor[d], 1);
  csr[pos] = (unsigned short)s;
}

// ---------------- prep: weight packing + zero deg/cursor (one dispatch) ----------------
// blocks 0..383: Bp chunks (which = bid>>7, c = bid&127)
// blocks 384..479: Pp chunks (b = bid-384)
// all blocks: zero one 256-int slice of deg|cursor.

__global__ void prep_k(const float* __restrict__ W1, const float* __restrict__ W2,
                       const float* __restrict__ W3, const float* __restrict__ l1w,
                       __half* __restrict__ B1, __half* __restrict__ B2,
                       __half* __restrict__ B3, __half* __restrict__ Pp,
                       int* __restrict__ deg, int* __restrict__ cursor) {
  int bid = blockIdx.x;
  int t = threadIdx.x;
  if (bid < 384) {
    int which = bid >> 7;
    int c = bid & 127;
    const float* W = which == 0 ? W1 : (which == 1 ? W2 : W3);
    __half* Bp = which == 0 ? B1 : (which == 1 ? B2 : B3);
    int kq = c >> 4, wcf = c & 15;
    int l = t >> 2;
    int j0 = (t & 3) * 2;
    int li = l & 15, lg = l >> 4;
    int n = wcf * 16 + li;
    int k = kq * 32 + lg * 8 + j0;
    __half2 v;
    v.x = __float2half_rn(W[(size_t)k * 256 + n]);
    v.y = __float2half_rn(W[(size_t)(k + 1) * 256 + n]);
    *reinterpret_cast<__half2*>(Bp + (size_t)c * 512 + 2 * t) = v;
  } else {
    int b = bid - 384;
    int l = b >> 4, cp = b & 15;
    int kq = cp >> 1, hh = cp & 1;
    int ln = t >> 2;
    int j0 = (t & 3) * 2;
    int li = ln & 15, lg = ln >> 4;
    int dim = hh * 16 + li;
    int k = kq * 32 + lg * 8 + j0;
    __half2 v;
    v.x = __float2half_rn(l1w[((size_t)l * 256 + k) * 32 + dim]);
    v.y = __float2half_rn(l1w[((size_t)l * 256 + k + 1) * 32 + dim]);
    *reinterpret_cast<__half2*>(Pp + (size_t)b * 512 + 2 * t) = v;
  }
  int z = bid * 256 + t;
  if (z < NNODES) deg[z] = 0;
  else if (z < 2 * NNODES) cursor[z - NNODES] = 0;
}

// ---------------- GEMM body: BM=32, BN=256 (full N, one block per row-tile) ----------
// 4 waves: wr2=wid>>1 (rows 16), wcl=wid&1 (col half 128). acc = 8 f32x4.
// proj: p += mfma(Pp frag[wcl], a) -> part[rows][dims wcl*16..+16].

__device__ __forceinline__ void gemm_body256(
    _Float16 (*As)[LDA], int m0, int tid,
    const __half* __restrict__ Bp, const __half* __restrict__ Pp,
    const float* __restrict__ dinv, __half* __restrict__ Y,
    float* __restrict__ part) {
  const int lane = tid & 63;
  const int wid = tid >> 6;
  const int wr2 = wid >> 1, wcl = wid & 1;
  const int li = lane & 15, lg = lane >> 4;

  f32x4 acc[8];
  #pragma unroll
  for (int j = 0; j < 8; ++j) acc[j] = (f32x4){0.f, 0.f, 0.f, 0.f};
  f32x4 p = (f32x4){0.f, 0.f, 0.f, 0.f};

  const __half* bwave = Bp + (size_t)(wcl * 8) * 512 + lane * 8;
  const __half* pbase = Pp + (size_t)wcl * 512 + lane * 8;

  #pragma unroll
  for (int kq = 0; kq < 8; ++kq) {
    f16x8 a = *reinterpret_cast<const f16x8*>(&As[wr2 * 16 + li][kq * 32 + lg * 8]);
    {
      f16x8 b0 = *reinterpret_cast<const f16x8*>(bwave + ((size_t)kq * 16 + 0) * 512);
      f16x8 b1 = *reinterpret_cast<const f16x8*>(bwave + ((size_t)kq * 16 + 1) * 512);
      f16x8 b2 = *reinterpret_cast<const f16x8*>(bwave + ((size_t)kq * 16 + 2) * 512);
      f16x8 b3 = *reinterpret_cast<const f16x8*>(bwave + ((size_t)kq * 16 + 3) * 512);
      acc[0] = __builtin_amdgcn_mfma_f32_16x16x32_f16(b0, a, acc[0], 0, 0, 0);
      acc[1] = __builtin_amdgcn_mfma_f32_16x16x32_f16(b1, a, acc[1], 0, 0, 0);
      acc[2] = __builtin_amdgcn_mfma_f32_16x16x32_f16(b2, a, acc[2], 0, 0, 0);
      acc[3] = __builtin_amdgcn_mfma_f32_16x16x32_f16(b3, a, acc[3], 0, 0, 0);
    }
    {
      f16x8 b4 = *reinterpret_cast<const f16x8*>(bwave + ((size_t)kq * 16 + 4) * 512);
      f16x8 b5 = *reinterpret_cast<const f16x8*>(bwave + ((size_t)kq * 16 + 5) * 512);
      f16x8 b6 = *reinterpret_cast<const f16x8*>(bwave + ((size_t)kq * 16 + 6) * 512);
      f16x8 b7 = *reinterpret_cast<const f16x8*>(bwave + ((size_t)kq * 16 + 7) * 512);
      acc[4] = __builtin_amdgcn_mfma_f32_16x16x32_f16(b4, a, acc[4], 0, 0, 0);
      acc[5] = __builtin_amdgcn_mfma_f32_16x16x32_f16(b5, a, acc[5], 0, 0, 0);
      acc[6] = __builtin_amdgcn_mfma_f32_16x16x32_f16(b6, a, acc[6], 0, 0, 0);
      acc[7] = __builtin_amdgcn_mfma_f32_16x16x32_f16(b7, a, acc[7], 0, 0, 0);
    }
    {
      f16x8 bp = *reinterpret_cast<const f16x8*>(pbase + (size_t)kq * 2 * 512);
      p = __builtin_amdgcn_mfma_f32_16x16x32_f16(bp, a, p, 0, 0, 0);
    }
  }

  __syncthreads();   // all waves done reading As; safe to overwrite

  {
    int row = wr2 * 16 + li;
    int r = m0 + row;
    float dv = dinv[r];
    #pragma unroll
    for (int cf = 0; cf < 8; ++cf) {
      int col = wcl * 128 + cf * 16 + lg * 4;
      H4 o;
      o.h[0].x = __float2half_rn(acc[cf][0] * dv);
      o.h[0].y = __float2half_rn(acc[cf][1] * dv);
      o.h[1].x = __float2half_rn(acc[cf][2] * dv);
      o.h[1].y = __float2half_rn(acc[cf][3] * dv);
      *reinterpret_cast<H4*>(&As[row][col]) = o;
    }
    float4 v;
    v.x = p[0]; v.y = p[1]; v.z = p[2]; v.w = p[3];
    *reinterpret_cast<float4*>(part + (size_t)r * 32 + wcl * 16 + lg * 4) = v;
  }

  __syncthreads();

  // store 32 rows x 256 halves: 1024 H8, 4 per thread (coalesced)
  #pragma unroll
  for (int l = 0; l < 4; ++l) {
    int f = l * 256 + tid;
    int row = f >> 5, c8 = (f & 31) * 8;
    *reinterpret_cast<H8*>(Y + (size_t)(m0 + row) * 256 + c8) =
        *reinterpret_cast<const H8*>(&As[row][c8]);
  }
}

// ---------------- layer 0: fp32 state -> fp16 LDS, gemm W1, proj p5 ----------------

__launch_bounds__(256, 5)
__global__ void gemm0_k(const float* __restrict__ Xf, const __half* __restrict__ Bp,
                        const float* __restrict__ dinv, __half* __restrict__ Y,
                        const __half* __restrict__ Pp, float* __restrict__ part) {
  __shared__ _Float16 As[32][LDA];
  const int tid = threadIdx.x;
  const int m0 = blockIdx.x * 32;
  #pragma unroll
  for (int l = 0; l < 4; ++l) {
    int f = l * 256 + tid;
    int row = f >> 5, c8 = (f & 31) * 8;
    const float* src = Xf + (size_t)(m0 + row) * 256 + c8;
    float4 u = *reinterpret_cast<const float4*>(src);
    float4 v = *reinterpret_cast<const float4*>(src + 4);
    H8 o;
    o.h[0].x = __float2half_rn(u.x); o.h[0].y = __float2half_rn(u.y);
    o.h[1].x = __float2half_rn(u.z); o.h[1].y = __float2half_rn(u.w);
    o.h[2].x = __float2half_rn(v.x); o.h[2].y = __float2half_rn(v.y);
    o.h[3].x = __float2half_rn(v.z); o.h[3].y = __float2half_rn(v.w);
    *reinterpret_cast<H8*>(&As[row][c8]) = o;
  }
  __syncthreads();
  gemm_body256(As, m0, tid, Bp, Pp, dinv, Y, part);
}

// ---------------- layers 1..4: fp16 activations from global, gemm, proj ----------------

__launch_bounds__(256, 5)
__global__ void gemm_k(const __half* __restrict__ Xh, const __half* __restrict__ Bp,
                       const float* __restrict__ dinv, __half* __restrict__ Y,
                       const __half* __restrict__ Pp, float* __restrict__ part) {
  __shared__ _Float16 As[32][LDA];
  const int tid = threadIdx.x;
  const int m0 = blockIdx.x * 32;
  #pragma unroll
  for (int l = 0; l < 4; ++l) {
    int f = l * 256 + tid;
    int row = f >> 5, c8 = (f & 31) * 8;
    *reinterpret_cast<H8*>(&As[row][c8]) =
        *reinterpret_cast<const H8*>(Xh + (size_t)(m0 + row) * 256 + c8);
  }
  __syncthreads();
  gemm_body256(As, m0, tid, Bp, Pp, dinv, Y, part);
}

// ---------------- gather (r5 proven shape): half-wave per node ----------------

__device__ inline void addH8(float* acc, const H8& v) {
  #pragma unroll
  for (int q = 0; q < 4; ++q) {
    acc[q * 2 + 0] += __low2float(v.h[q]);
    acc[q * 2 + 1] += __high2float(v.h[q]);
  }
}

__global__ void gather_k(const __half* __restrict__ ysh, const int* __restrict__ rs,
                         const unsigned short* __restrict__ csr, const float* __restrict__ dinv,
                         const float* __restrict__ bias, __half* __restrict__ out) {
  int tid = threadIdx.x;
  int lane = tid & 63;
  int wave = (blockIdx.x * blockDim.x + tid) >> 6;
  int d = wave * 2 + (lane >> 5);
  int c8 = (lane & 31) * 8;

  float acc[8];
  H8 self = *reinterpret_cast<const H8*>(ysh + (size_t)d * 256 + c8);
  #pragma unroll
  for (int q = 0; q < 4; ++q) {
    acc[q * 2 + 0] = __low2float(self.h[q]);
    acc[q * 2 + 1] = __high2float(self.h[q]);
  }

  int e = rs[d], end = rs[d + 1];
  for (; e + 3 < end; e += 4) {
    int s0 = csr[e], s1 = csr[e + 1], s2 = csr[e + 2], s3 = csr[e + 3];
    H8 v0 = *reinterpret_cast<const H8*>(ysh + (size_t)s0 * 256 + c8);
    H8 v1 = *reinterpret_cast<const H8*>(ysh + (size_t)s1 * 256 + c8);
    H8 v2 = *reinterpret_cast<const H8*>(ysh + (size_t)s2 * 256 + c8);
    H8 v3 = *reinterpret_cast<const H8*>(ysh + (size_t)s3 * 256 + c8);
    addH8(acc, v0);
    addH8(acc, v1);
    addH8(acc, v2);
    addH8(acc, v3);
  }
  for (; e < end; ++e) {
    int s0 = csr[e];
    H8 v0 = *reinterpret_cast<const H8*>(ysh + (size_t)s0 * 256 + c8);
    addH8(acc, v0);
  }

  float dv = dinv[d];
  float4 b0 = *reinterpret_cast<const float4*>(bias + c8);
  float4 b1 = *reinterpret_cast<const float4*>(bias + c8 + 4);
  float r0 = fmaxf(acc[0] * dv + b0.x, 0.f);
  float r1 = fmaxf(acc[1] * dv + b0.y, 0.f);
  float r2 = fmaxf(acc[2] * dv + b0.z, 0.f);
  float r3 = fmaxf(acc[3] * dv + b0.w, 0.f);
  float r4 = fmaxf(acc[4] * dv + b1.x, 0.f);
  float r5 = fmaxf(acc[5] * dv + b1.y, 0.f);
  float r6 = fmaxf(acc[6] * dv + b1.z, 0.f);
  float r7 = fmaxf(acc[7] * dv + b1.w, 0.f);
  H8 o;
  o.h[0].x = __float2half_rn(r0); o.h[0].y = __float2half_rn(r1);
  o.h[1].x = __float2half_rn(r2); o.h[1].y = __float2half_rn(r3);
  o.h[2].x = __float2half_rn(r4); o.h[2].y = __float2half_rn(r5);
  o.h[3].x = __float2half_rn(r6); o.h[3].y = __float2half_rn(r7);
  *reinterpret_cast<H8*>(out + (size_t)d * 256 + c8) = o;
}

// ---------------- fused MLP + readout (+ in-block p4 = o5 @ lw4) ----------------

__launch_bounds__(192)
__global__ void mlpfinal_k(const float* __restrict__ p0, const float* __restrict__ p1,
                           const float* __restrict__ p2, const float* __restrict__ p3,
                           const float* __restrict__ p5, const __half* __restrict__ o5h,
                           const float* __restrict__ lw4,
                           const float* __restrict__ action, const float* __restrict__ l1wlast,
                           const float* __restrict__ l1b, const float* __restrict__ l2w,
                           const float* __restrict__ l2b, const float* __restrict__ l3w,
                           const float* __restrict__ l3b, float* __restrict__ out) {
  __shared__ float w2s[1024];
  __shared__ __half o5s[6][256];
  __shared__ float h1s[6][33];
  __shared__ float red[3];
  int tid = threadIdx.x;
  for (int i = tid; i < 1024; i += 192) w2s[i] = l2w[i];
  {
    // stage o5 rows for this graph: 6 rows x 256 halves = 192 H8 units
    int row = tid >> 5, c8 = (tid & 31) * 8;
    *reinterpret_cast<H8*>(&o5s[row][c8]) =
        *reinterpret_cast<const H8*>(o5h + ((size_t)blockIdx.x * 6 + row) * 256 + c8);
  }
  __syncthreads();
  int a = tid >> 5, dim = tid & 31;
  int n = blockIdx.x * 6 + a;
  int idx = n * 32 + dim;
  float p4 = 0.f;
  #pragma unroll 8
  for (int k = 0; k < 256; ++k)
    p4 += __half2float(o5s[a][k]) * lw4[k * 32 + dim];
  float h1 = l1b[dim] + action[n] * l1wlast[dim]
           + p0[idx] + p1[idx] + p2[idx] + p3[idx] + p4 + p5[idx];
  h1s[a][dim] = fmaxf(h1, 0.f);
  __syncthreads();
  float acc = l2b[dim];
  #pragma unroll
  for (int k = 0; k < 32; ++k) acc += h1s[a][k] * w2s[k * 32 + dim];
  float v = fmaxf(acc, 0.f) * l3w[dim];
  #pragma unroll
  for (int off = 32; off; off >>= 1) v += __shfl_down(v, off, 64);
  int lane = tid & 63, wave = tid >> 6;
  if (lane == 0) red[wave] = v;
  __syncthreads();
  if (tid == 0) out[blockIdx.x] = red[0] + red[1] + red[2] + l3b[0];
}

// ---------------- host ----------------

extern "C" void kernel_launch(void* const* d_in, const int* in_sizes, int n_in,
                              void* d_out, int out_size, void* d_ws, size_t ws_size,
                              hipStream_t stream) {
  const float* state  = (const float*)d_in[0];
  const int*   ei     = (const int*)d_in[1];
  const float* action = (const float*)d_in[2];
  const float* W1 = (const float*)d_in[3];
  const float* b1 = (const float*)d_in[4];
  const float* W2 = (const float*)d_in[5];
  const float* b2 = (const float*)d_in[6];
  const float* W3 = (const float*)d_in[7];
  const float* b3 = (const float*)d_in[8];
  const float* l1w = (const float*)d_in[13];
  const float* l1b = (const float*)d_in[14];
  const float* l2w = (const float*)d_in[15];
  const float* l2b = (const float*)d_in[16];
  const float* l3w = (const float*)d_in[17];
  const float* l3b = (const float*)d_in[18];
  float* out = (float*)d_out;

  char* base = (char*)d_ws;
  size_t off = 0;
  auto carve = [&](size_t bytes) {
    char* q = base + off;
    off += (bytes + 255) & ~(size_t)255;
    return q;
  };
  __half* ysh   = (__half*)carve((size_t)NNODES * 256 * 2);
  __half* obufh = (__half*)carve((size_t)NNODES * 256 * 2);
  __half* Bp1   = (__half*)carve(128 * 512 * 2);
  __half* Bp2   = (__half*)carve(128 * 512 * 2);
  __half* Bp3   = (__half*)carve(128 * 512 * 2);
  __half* Pp    = (__half*)carve(96 * 512 * 2);   // 6 slices x 16 chunks
  float* parts[6];
  for (int i = 0; i < 6; ++i) parts[i] = (float*)carve((size_t)NNODES * 32 * 4);
  float* dinv  = (float*)carve(NNODES * 4);
  int*   deg   = (int*)carve(NNODES * 4);
  int*   cursor= (int*)carve(NNODES * 4);
  int*   rs    = (int*)carve((NNODES + 1) * 4);
  unsigned short* csr = (unsigned short*)carve((size_t)NEDGES * 2);
  int*   bsum  = (int*)carve(256 * 4);

  // prep: pack weights + zero deg/cursor (replaces wpack, lwpack, memset)
  prep_k<<<480, 256, 0, stream>>>(W1, W2, W3, l1w, Bp1, Bp2, Bp3, Pp, deg, cursor);

  count_deg_k<<<NEDGES / 256, 256, 0, stream>>>(ei, deg);
  int nb = (NNODES + 255) / 256;
  scan1_k<<<nb, 256, 0, stream>>>(deg, rs, bsum, dinv);
  scan2_k<<<1, 256, 0, stream>>>(bsum, nb);
  scan3_k<<<nb, 256, 0, stream>>>(rs, bsum);
  scatter_k<<<NEDGES / 256, 256, 0, stream>>>(ei, rs, cursor, csr);

  int gblocks = NNODES / 32;   // 1875
  const __half* Bps[5] = {Bp1, Bp2, Bp3, Bp3, Bp3};
  const float*  bs[5]  = {b1, b2, b3, b3, b3};

  // layer 0: state @ W1 -> ysh ; proj p5 (state @ lw5)
  gemm0_k<<<gblocks, 256, 0, stream>>>(state, Bp1, dinv, ysh,
                                       Pp + (size_t)5 * 16 * 512, parts[5]);
  for (int layer = 1; layer < 5; ++layer) {
    gather_k<<<NNODES / 8, 256, 0, stream>>>(ysh, rs, csr, dinv, bs[layer - 1], obufh);
    gemm_k<<<gblocks, 256, 0, stream>>>(obufh, Bps[layer], dinv, ysh,
                                        Pp + (size_t)(layer - 1) * 16 * 512, parts[layer - 1]);
  }
  // layer 5: gather -> o5 (p4 computed inside mlpfinal)
  gather_k<<<NNODES / 8, 256, 0, stream>>>(ysh, rs, csr, dinv, b3, obufh);

  mlpfinal_k<<<NGRAPH, 192, 0, stream>>>(parts[0], parts[1], parts[2], parts[3], parts[5],
                                         obufh, l1w + 1024 * 32, action, l1w + 1536 * 32,
                                         l1b, l2w, l2b, l3w, l3b, out);
}

// Round 14
// 618.672 us; speedup vs baseline: 1.0565x; 1.0565x over previous
//
#include <hip/hip_runtime.h>
#include <hip/hip_fp16.h>

#define NNODES 60000
#define NEDGES 960000
#define NGRAPH 10000

struct __align__(16) H8 { __half2 h[4]; };
struct __align__(8)  H4 { __half2 h[2]; };

typedef _Float16 f16x8 __attribute__((ext_vector_type(8)));
typedef float f32x4 __attribute__((ext_vector_type(4)));

#define LDA 264   // halves; 528 B row stride (16B-aligned rows)

// ---------------- degree / CSR build ----------------

__global__ void count_deg_k(const int* __restrict__ ei, int* __restrict__ deg) {
  int e = blockIdx.x * blockDim.x + threadIdx.x;
  atomicAdd(&deg[ei[NEDGES + e]], 1);
}

__global__ void scan1_k(const int* __restrict__ deg, int* __restrict__ rs,
                        int* __restrict__ bsum, float* __restrict__ dinv) {
  __shared__ int s[256];
  int tid = threadIdx.x;
  int i = blockIdx.x * 256 + tid;
  int v = (i < NNODES) ? deg[i] : 0;
  if (i < NNODES) dinv[i] = rsqrtf((float)v + 1.0f);
  int x = v;
  s[tid] = x; __syncthreads();
  #pragma unroll
  for (int off = 1; off < 256; off <<= 1) {
    int t = (tid >= off) ? s[tid - off] : 0;
    __syncthreads();
    x += t; s[tid] = x; __syncthreads();
  }
  if (i < NNODES) rs[i] = x - v;
  if (tid == 255) bsum[blockIdx.x] = x;
}

__global__ void scan2_k(int* __restrict__ bsum, int nb) {
  __shared__ int s[256];
  int tid = threadIdx.x;
  int v = (tid < nb) ? bsum[tid] : 0;
  int x = v; s[tid] = x; __syncthreads();
  #pragma unroll
  for (int off = 1; off < 256; off <<= 1) {
    int t = (tid >= off) ? s[tid - off] : 0;
    __syncthreads();
    x += t; s[tid] = x; __syncthreads();
  }
  if (tid < nb) bsum[tid] = x - v;
}

__global__ void scan3_k(int* __restrict__ rs, const int* __restrict__ bsum) {
  int i = blockIdx.x * 256 + threadIdx.x;
  if (i < NNODES) rs[i] += bsum[blockIdx.x];
  if (i == 0) rs[NNODES] = NEDGES;
}

__global__ void scatter_k(const int* __restrict__ ei, const int* __restrict__ rs,
                          int* __restrict__ cursor, unsigned short* __restrict__ csr) {
  int e = blockIdx.x * blockDim.x + threadIdx.x;
  int s = ei[e], d = ei[NEDGES + e];
  int pos = rs[d] + atomicAdd(&cursor[d], 1);
  csr[pos] = (unsigned short)s;
}

// ---------------- prep: weight packing + zero deg/cursor (one dispatch) ----------------

__global__ void prep_k(const float* __restrict__ W1, const float* __restrict__ W2,
                       const float* __restrict__ W3, const float* __restrict__ l1w,
                       __half* __restrict__ B1, __half* __restrict__ B2,
                       __half* __restrict__ B3, __half* __restrict__ Pp,
                       int* __restrict__ deg, int* __restrict__ cursor) {
  int bid = blockIdx.x;
  int t = threadIdx.x;
  if (bid < 384) {
    int which = bid >> 7;
    int c = bid & 127;
    const float* W = which == 0 ? W1 : (which == 1 ? W2 : W3);
    __half* Bp = which == 0 ? B1 : (which == 1 ? B2 : B3);
    int kq = c >> 4, wcf = c & 15;
    int l = t >> 2;
    int j0 = (t & 3) * 2;
    int li = l & 15, lg = l >> 4;
    int n = wcf * 16 + li;
    int k = kq * 32 + lg * 8 + j0;
    __half2 v;
    v.x = __float2half_rn(W[(size_t)k * 256 + n]);
    v.y = __float2half_rn(W[(size_t)(k + 1) * 256 + n]);
    *reinterpret_cast<__half2*>(Bp + (size_t)c * 512 + 2 * t) = v;
  } else {
    int b = bid - 384;
    int l = b >> 4, cp = b & 15;
    int kq = cp >> 1, hh = cp & 1;
    int ln = t >> 2;
    int j0 = (t & 3) * 2;
    int li = ln & 15, lg = ln >> 4;
    int dim = hh * 16 + li;
    int k = kq * 32 + lg * 8 + j0;
    __half2 v;
    v.x = __float2half_rn(l1w[((size_t)l * 256 + k) * 32 + dim]);
    v.y = __float2half_rn(l1w[((size_t)l * 256 + k + 1) * 32 + dim]);
    *reinterpret_cast<__half2*>(Pp + (size_t)b * 512 + 2 * t) = v;
  }
  int z = bid * 256 + t;
  if (z < NNODES) deg[z] = 0;
  else if (z < 2 * NNODES) cursor[z - NNODES] = 0;
}

// ---------------- GEMM body: BM=32, BN=256 (full N, one block per row-tile) ----------

__device__ __forceinline__ void gemm_body256(
    _Float16 (*As)[LDA], int m0, int tid,
    const __half* __restrict__ Bp, const __half* __restrict__ Pp,
    const float* __restrict__ dinv, __half* __restrict__ Y,
    float* __restrict__ part) {
  const int lane = tid & 63;
  const int wid = tid >> 6;
  const int wr2 = wid >> 1, wcl = wid & 1;
  const int li = lane & 15, lg = lane >> 4;

  f32x4 acc[8];
  #pragma unroll
  for (int j = 0; j < 8; ++j) acc[j] = (f32x4){0.f, 0.f, 0.f, 0.f};
  f32x4 p = (f32x4){0.f, 0.f, 0.f, 0.f};

  const __half* bwave = Bp + (size_t)(wcl * 8) * 512 + lane * 8;
  const __half* pbase = Pp + (size_t)wcl * 512 + lane * 8;

  #pragma unroll
  for (int kq = 0; kq < 8; ++kq) {
    f16x8 a = *reinterpret_cast<const f16x8*>(&As[wr2 * 16 + li][kq * 32 + lg * 8]);
    {
      f16x8 b0 = *reinterpret_cast<const f16x8*>(bwave + ((size_t)kq * 16 + 0) * 512);
      f16x8 b1 = *reinterpret_cast<const f16x8*>(bwave + ((size_t)kq * 16 + 1) * 512);
      f16x8 b2 = *reinterpret_cast<const f16x8*>(bwave + ((size_t)kq * 16 + 2) * 512);
      f16x8 b3 = *reinterpret_cast<const f16x8*>(bwave + ((size_t)kq * 16 + 3) * 512);
      acc[0] = __builtin_amdgcn_mfma_f32_16x16x32_f16(b0, a, acc[0], 0, 0, 0);
      acc[1] = __builtin_amdgcn_mfma_f32_16x16x32_f16(b1, a, acc[1], 0, 0, 0);
      acc[2] = __builtin_amdgcn_mfma_f32_16x16x32_f16(b2, a, acc[2], 0, 0, 0);
      acc[3] = __builtin_amdgcn_mfma_f32_16x16x32_f16(b3, a, acc[3], 0, 0, 0);
    }
    {
      f16x8 b4 = *reinterpret_cast<const f16x8*>(bwave + ((size_t)kq * 16 + 4) * 512);
      f16x8 b5 = *reinterpret_cast<const f16x8*>(bwave + ((size_t)kq * 16 + 5) * 512);
      f16x8 b6 = *reinterpret_cast<const f16x8*>(bwave + ((size_t)kq * 16 + 6) * 512);
      f16x8 b7 = *reinterpret_cast<const f16x8*>(bwave + ((size_t)kq * 16 + 7) * 512);
      acc[4] = __builtin_amdgcn_mfma_f32_16x16x32_f16(b4, a, acc[4], 0, 0, 0);
      acc[5] = __builtin_amdgcn_mfma_f32_16x16x32_f16(b5, a, acc[5], 0, 0, 0);
      acc[6] = __builtin_amdgcn_mfma_f32_16x16x32_f16(b6, a, acc[6], 0, 0, 0);
      acc[7] = __builtin_amdgcn_mfma_f32_16x16x32_f16(b7, a, acc[7], 0, 0, 0);
    }
    {
      f16x8 bp = *reinterpret_cast<const f16x8*>(pbase + (size_t)kq * 2 * 512);
      p = __builtin_amdgcn_mfma_f32_16x16x32_f16(bp, a, p, 0, 0, 0);
    }
  }

  __syncthreads();   // all waves done reading As; safe to overwrite

  {
    int row = wr2 * 16 + li;
    int r = m0 + row;
    float dv = dinv[r];
    #pragma unroll
    for (int cf = 0; cf < 8; ++cf) {
      int col = wcl * 128 + cf * 16 + lg * 4;
      H4 o;
      o.h[0].x = __float2half_rn(acc[cf][0] * dv);
      o.h[0].y = __float2half_rn(acc[cf][1] * dv);
      o.h[1].x = __float2half_rn(acc[cf][2] * dv);
      o.h[1].y = __float2half_rn(acc[cf][3] * dv);
      *reinterpret_cast<H4*>(&As[row][col]) = o;
    }
    float4 v;
    v.x = p[0]; v.y = p[1]; v.z = p[2]; v.w = p[3];
    *reinterpret_cast<float4*>(part + (size_t)r * 32 + wcl * 16 + lg * 4) = v;
  }

  __syncthreads();

  // store 32 rows x 256 halves: 1024 H8, 4 per thread (coalesced)
  #pragma unroll
  for (int l = 0; l < 4; ++l) {
    int f = l * 256 + tid;
    int row = f >> 5, c8 = (f & 31) * 8;
    *reinterpret_cast<H8*>(Y + (size_t)(m0 + row) * 256 + c8) =
        *reinterpret_cast<const H8*>(&As[row][c8]);
  }
}

// ---------------- layer 0: fp32 state -> fp16 LDS, gemm W1, proj p5 ----------------

__launch_bounds__(256, 5)
__global__ void gemm0_k(const float* __restrict__ Xf, const __half* __restrict__ Bp,
                        const float* __restrict__ dinv, __half* __restrict__ Y,
                        const __half* __restrict__ Pp, float* __restrict__ part) {
  __shared__ _Float16 As[32][LDA];
  const int tid = threadIdx.x;
  const int m0 = blockIdx.x * 32;
  #pragma unroll
  for (int l = 0; l < 4; ++l) {
    int f = l * 256 + tid;
    int row = f >> 5, c8 = (f & 31) * 8;
    const float* src = Xf + (size_t)(m0 + row) * 256 + c8;
    float4 u = *reinterpret_cast<const float4*>(src);
    float4 v = *reinterpret_cast<const float4*>(src + 4);
    H8 o;
    o.h[0].x = __float2half_rn(u.x); o.h[0].y = __float2half_rn(u.y);
    o.h[1].x = __float2half_rn(u.z); o.h[1].y = __float2half_rn(u.w);
    o.h[2].x = __float2half_rn(v.x); o.h[2].y = __float2half_rn(v.y);
    o.h[3].x = __float2half_rn(v.z); o.h[3].y = __float2half_rn(v.w);
    *reinterpret_cast<H8*>(&As[row][c8]) = o;
  }
  __syncthreads();
  gemm_body256(As, m0, tid, Bp, Pp, dinv, Y, part);
}

// ---------------- layers 1..4: fp16 activations from global, gemm, proj ----------------

__launch_bounds__(256, 5)
__global__ void gemm_k(const __half* __restrict__ Xh, const __half* __restrict__ Bp,
                       const float* __restrict__ dinv, __half* __restrict__ Y,
                       const __half* __restrict__ Pp, float* __restrict__ part) {
  __shared__ _Float16 As[32][LDA];
  const int tid = threadIdx.x;
  const int m0 = blockIdx.x * 32;
  #pragma unroll
  for (int l = 0; l < 4; ++l) {
    int f = l * 256 + tid;
    int row = f >> 5, c8 = (f & 31) * 8;
    *reinterpret_cast<H8*>(&As[row][c8]) =
        *reinterpret_cast<const H8*>(Xh + (size_t)(m0 + row) * 256 + c8);
  }
  __syncthreads();
  gemm_body256(As, m0, tid, Bp, Pp, dinv, Y, part);
}

// ---------------- proj-only (o5 -> p4): MFMA projection ----------------

__launch_bounds__(256, 4)
__global__ void proj_k(const __half* __restrict__ Xh, const __half* __restrict__ Pp,
                       float* __restrict__ part) {
  __shared__ _Float16 As[64][LDA];
  const int tid = threadIdx.x;
  const int m0 = blockIdx.x * 64;
  #pragma unroll
  for (int l = 0; l < 8; ++l) {
    int f = l * 256 + tid;
    int row = f >> 5, c8 = (f & 31) * 8;
    *reinterpret_cast<H8*>(&As[row][c8]) =
        *reinterpret_cast<const H8*>(Xh + (size_t)(m0 + row) * 256 + c8);
  }
  __syncthreads();

  const int lane = tid & 63;
  const int wid = tid >> 6;
  const int li = lane & 15, lg = lane >> 4;
  const __half* pbase = Pp + lane * 8;

  f32x4 p0 = (f32x4){0.f, 0.f, 0.f, 0.f};
  f32x4 p1 = (f32x4){0.f, 0.f, 0.f, 0.f};
  #pragma unroll
  for (int kq = 0; kq < 8; ++kq) {
    int k0 = kq * 32;
    f16x8 ap = *reinterpret_cast<const f16x8*>(&As[wid * 16 + li][k0 + lg * 8]);
    f16x8 bp0 = *reinterpret_cast<const f16x8*>(pbase + ((size_t)kq * 2 + 0) * 512);
    f16x8 bp1 = *reinterpret_cast<const f16x8*>(pbase + ((size_t)kq * 2 + 1) * 512);
    p0 = __builtin_amdgcn_mfma_f32_16x16x32_f16(bp0, ap, p0, 0, 0, 0);
    p1 = __builtin_amdgcn_mfma_f32_16x16x32_f16(bp1, ap, p1, 0, 0, 0);
  }
  int pr = m0 + wid * 16 + li;
  {
    float4 v0, v1;
    v0.x = p0[0]; v0.y = p0[1]; v0.z = p0[2]; v0.w = p0[3];
    v1.x = p1[0]; v1.y = p1[1]; v1.z = p1[2]; v1.w = p1[3];
    *reinterpret_cast<float4*>(part + (size_t)pr * 32 + lg * 4) = v0;
    *reinterpret_cast<float4*>(part + (size_t)pr * 32 + 16 + lg * 4) = v1;
  }
}

// ---------------- gather (r5 proven shape): half-wave per node ----------------

__device__ inline void addH8(float* acc, const H8& v) {
  #pragma unroll
  for (int q = 0; q < 4; ++q) {
    acc[q * 2 + 0] += __low2float(v.h[q]);
    acc[q * 2 + 1] += __high2float(v.h[q]);
  }
}

__global__ void gather_k(const __half* __restrict__ ysh, const int* __restrict__ rs,
                         const unsigned short* __restrict__ csr, const float* __restrict__ dinv,
                         const float* __restrict__ bias, __half* __restrict__ out) {
  int tid = threadIdx.x;
  int lane = tid & 63;
  int wave = (blockIdx.x * blockDim.x + tid) >> 6;
  int d = wave * 2 + (lane >> 5);
  int c8 = (lane & 31) * 8;

  float acc[8];
  H8 self = *reinterpret_cast<const H8*>(ysh + (size_t)d * 256 + c8);
  #pragma unroll
  for (int q = 0; q < 4; ++q) {
    acc[q * 2 + 0] = __low2float(self.h[q]);
    acc[q * 2 + 1] = __high2float(self.h[q]);
  }

  int e = rs[d], end = rs[d + 1];
  for (; e + 3 < end; e += 4) {
    int s0 = csr[e], s1 = csr[e + 1], s2 = csr[e + 2], s3 = csr[e + 3];
    H8 v0 = *reinterpret_cast<const H8*>(ysh + (size_t)s0 * 256 + c8);
    H8 v1 = *reinterpret_cast<const H8*>(ysh + (size_t)s1 * 256 + c8);
    H8 v2 = *reinterpret_cast<const H8*>(ysh + (size_t)s2 * 256 + c8);
    H8 v3 = *reinterpret_cast<const H8*>(ysh + (size_t)s3 * 256 + c8);
    addH8(acc, v0);
    addH8(acc, v1);
    addH8(acc, v2);
    addH8(acc, v3);
  }
  for (; e < end; ++e) {
    int s0 = csr[e];
    H8 v0 = *reinterpret_cast<const H8*>(ysh + (size_t)s0 * 256 + c8);
    addH8(acc, v0);
  }

  float dv = dinv[d];
  float4 b0 = *reinterpret_cast<const float4*>(bias + c8);
  float4 b1 = *reinterpret_cast<const float4*>(bias + c8 + 4);
  float r0 = fmaxf(acc[0] * dv + b0.x, 0.f);
  float r1 = fmaxf(acc[1] * dv + b0.y, 0.f);
  float r2 = fmaxf(acc[2] * dv + b0.z, 0.f);
  float r3 = fmaxf(acc[3] * dv + b0.w, 0.f);
  float r4 = fmaxf(acc[4] * dv + b1.x, 0.f);
  float r5 = fmaxf(acc[5] * dv + b1.y, 0.f);
  float r6 = fmaxf(acc[6] * dv + b1.z, 0.f);
  float r7 = fmaxf(acc[7] * dv + b1.w, 0.f);
  H8 o;
  o.h[0].x = __float2half_rn(r0); o.h[0].y = __float2half_rn(r1);
  o.h[1].x = __float2half_rn(r2); o.h[1].y = __float2half_rn(r3);
  o.h[2].x = __float2half_rn(r4); o.h[2].y = __float2half_rn(r5);
  o.h[3].x = __float2half_rn(r6); o.h[3].y = __float2half_rn(r7);
  *reinterpret_cast<H8*>(out + (size_t)d * 256 + c8) = o;
}

// ---------------- fused MLP + readout ----------------

__launch_bounds__(192)
__global__ void mlpfinal_k(const float* __restrict__ p0, const float* __restrict__ p1,
                           const float* __restrict__ p2, const float* __restrict__ p3,
                           const float* __restrict__ p4, const float* __restrict__ p5,
                           const float* __restrict__ action, const float* __restrict__ l1wlast,
                           const float* __restrict__ l1b, const float* __restrict__ l2w,
                           const float* __restrict__ l2b, const float* __restrict__ l3w,
                           const float* __restrict__ l3b, float* __restrict__ out) {
  __shared__ float w2s[1024];
  __shared__ float h1s[6][33];
  __shared__ float red[3];
  int tid = threadIdx.x;
  for (int i = tid; i < 1024; i += 192) w2s[i] = l2w[i];
  int a = tid >> 5, dim = tid & 31;
  int n = blockIdx.x * 6 + a;
  int idx = n * 32 + dim;
  float h1 = l1b[dim] + action[n] * l1wlast[dim]
           + p0[idx] + p1[idx] + p2[idx] + p3[idx] + p4[idx] + p5[idx];
  h1s[a][dim] = fmaxf(h1, 0.f);
  __syncthreads();
  float acc = l2b[dim];
  #pragma unroll
  for (int k = 0; k < 32; ++k) acc += h1s[a][k] * w2s[k * 32 + dim];
  float v = fmaxf(acc, 0.f) * l3w[dim];
  #pragma unroll
  for (int off = 32; off; off >>= 1) v += __shfl_down(v, off, 64);
  int lane = tid & 63, wave = tid >> 6;
  if (lane == 0) red[wave] = v;
  __syncthreads();
  if (tid == 0) out[blockIdx.x] = red[0] + red[1] + red[2] + l3b[0];
}

// ---------------- host ----------------

extern "C" void kernel_launch(void* const* d_in, const int* in_sizes, int n_in,
                              void* d_out, int out_size, void* d_ws, size_t ws_size,
                              hipStream_t stream) {
  const float* state  = (const float*)d_in[0];
  const int*   ei     = (const int*)d_in[1];
  const float* action = (const float*)d_in[2];
  const float* W1 = (const float*)d_in[3];
  const float* b1 = (const float*)d_in[4];
  const float* W2 = (const float*)d_in[5];
  const float* b2 = (const float*)d_in[6];
  const float* W3 = (const float*)d_in[7];
  const float* b3 = (const float*)d_in[8];
  const float* l1w = (const float*)d_in[13];
  const float* l1b = (const float*)d_in[14];
  const float* l2w = (const float*)d_in[15];
  const float* l2b = (const float*)d_in[16];
  const float* l3w = (const float*)d_in[17];
  const float* l3b = (const float*)d_in[18];
  float* out = (float*)d_out;

  char* base = (char*)d_ws;
  size_t off = 0;
  auto carve = [&](size_t bytes) {
    char* q = base + off;
    off += (bytes + 255) & ~(size_t)255;
    return q;
  };
  __half* ysh   = (__half*)carve((size_t)NNODES * 256 * 2);
  __half* obufh = (__half*)carve((size_t)NNODES * 256 * 2);
  __half* Bp1   = (__half*)carve(128 * 512 * 2);
  __half* Bp2   = (__half*)carve(128 * 512 * 2);
  __half* Bp3   = (__half*)carve(128 * 512 * 2);
  __half* Pp    = (__half*)carve(96 * 512 * 2);   // 6 slices x 16 chunks
  float* parts[6];
  for (int i = 0; i < 6; ++i) parts[i] = (float*)carve((size_t)NNODES * 32 * 4);
  float* dinv  = (float*)carve(NNODES * 4);
  int*   deg   = (int*)carve(NNODES * 4);
  int*   cursor= (int*)carve(NNODES * 4);
  int*   rs    = (int*)carve((NNODES + 1) * 4);
  unsigned short* csr = (unsigned short*)carve((size_t)NEDGES * 2);
  int*   bsum  = (int*)carve(256 * 4);

  // prep: pack weights + zero deg/cursor (replaces wpack, lwpack, memset)
  prep_k<<<480, 256, 0, stream>>>(W1, W2, W3, l1w, Bp1, Bp2, Bp3, Pp, deg, cursor);

  count_deg_k<<<NEDGES / 256, 256, 0, stream>>>(ei, deg);
  int nb = (NNODES + 255) / 256;
  scan1_k<<<nb, 256, 0, stream>>>(deg, rs, bsum, dinv);
  scan2_k<<<1, 256, 0, stream>>>(bsum, nb);
  scan3_k<<<nb, 256, 0, stream>>>(rs, bsum);
  scatter_k<<<NEDGES / 256, 256, 0, stream>>>(ei, rs, cursor, csr);

  int gblocks = NNODES / 32;   // 1875
  const __half* Bps[5] = {Bp1, Bp2, Bp3, Bp3, Bp3};
  const float*  bs[5]  = {b1, b2, b3, b3, b3};

  // layer 0: state @ W1 -> ysh ; proj p5 (state @ lw5)
  gemm0_k<<<gblocks, 256, 0, stream>>>(state, Bp1, dinv, ysh,
                                       Pp + (size_t)5 * 16 * 512, parts[5]);
  for (int layer = 1; layer < 5; ++layer) {
    gather_k<<<NNODES / 8, 256, 0, stream>>>(ysh, rs, csr, dinv, bs[layer - 1], obufh);
    gemm_k<<<gblocks, 256, 0, stream>>>(obufh, Bps[layer], dinv, ysh,
                                        Pp + (size_t)(layer - 1) * 16 * 512, parts[layer - 1]);
  }
  // layer 5: gather -> o5 ; proj -> p4
  gather_k<<<NNODES / 8, 256, 0, stream>>>(ysh, rs, csr, dinv, b3, obufh);
  proj_k<<<NNODES / 64, 256, 0, stream>>>(obufh, Pp + (size_t)4 * 16 * 512, parts[4]);

  mlpfinal_k<<<NGRAPH, 192, 0, stream>>>(parts[0], parts[1], parts[2], parts[3], parts[4],
                                         parts[5], action, l1w + 1536 * 32, l1b, l2w, l2b,
                                         l3w, l3b, out);
}